// Round 2
// baseline (169.999 us; speedup 1.0000x reference)
//
#include <hip/hip_runtime.h>
#include <hip/hip_bf16.h>

typedef __bf16 bf16;
typedef __bf16 bf16x4 __attribute__((ext_vector_type(4)));
typedef __bf16 bf16x8 __attribute__((ext_vector_type(8)));
typedef float f32x4 __attribute__((ext_vector_type(4)));

#define NB 8
#define NN 1024
#define GIN 1024
#define GH 128
#define MROWS 8192  // NB*NN

static __device__ __forceinline__ f32x4 mfma16(bf16x8 a, bf16x8 b, f32x4 c) {
    return __builtin_amdgcn_mfma_f32_16x16x32_bf16(a, b, c, 0, 0, 0);
}

// ---------------- degree / dinv ----------------
// one wave per row; block=256 -> 4 rows/block; grid = 8192/4 = 2048
__global__ __launch_bounds__(256) void deg_kernel(const int* __restrict__ rpa,
                                                  float* __restrict__ dinv) {
    int row  = blockIdx.x * 4 + (threadIdx.x >> 6);  // 0..8191
    int lane = threadIdx.x & 63;
    int i = row & (NN - 1);
    const int4* p = reinterpret_cast<const int4*>(rpa + (size_t)row * NN);
    int cnt = 0;
#pragma unroll
    for (int it = 0; it < 4; ++it) {
        int4 v = p[lane + it * 64];
        int j = (lane + it * 64) * 4;
        cnt += (v.x != 0 && j + 0 != i);
        cnt += (v.y != 0 && j + 1 != i);
        cnt += (v.z != 0 && j + 2 != i);
        cnt += (v.w != 0 && j + 3 != i);
    }
#pragma unroll
    for (int off = 32; off > 0; off >>= 1) cnt += __shfl_down(cnt, off, 64);
    if (lane == 0) dinv[row] = rsqrtf((float)(cnt + 1));  // +1 self-loop
}

// ---------------- Ahat materialization (bf16) ----------------
// one block per row; 256 threads x 4 elements
__global__ __launch_bounds__(256) void ahat_kernel(const int* __restrict__ rpa,
                                                   const float* __restrict__ dinv,
                                                   bf16* __restrict__ Ahat) {
    int row = blockIdx.x;            // 0..8191
    int b = row >> 10, i = row & (NN - 1);
    float di = dinv[row];
    const int4*   rp = reinterpret_cast<const int4*>(rpa + (size_t)row * NN);
    const float4* dv = reinterpret_cast<const float4*>(dinv + b * NN);
    int t = threadIdx.x;
    int4   v  = rp[t];
    float4 dj = dv[t];
    int j = t * 4;
    bf16x4 o;
    o[0] = (bf16)(((v.x != 0 && j + 0 != i) || j + 0 == i) ? di * dj.x : 0.f);
    o[1] = (bf16)(((v.y != 0 && j + 1 != i) || j + 1 == i) ? di * dj.y : 0.f);
    o[2] = (bf16)(((v.z != 0 && j + 2 != i) || j + 2 == i) ? di * dj.z : 0.f);
    o[3] = (bf16)(((v.w != 0 && j + 3 != i) || j + 3 == i) ? di * dj.w : 0.f);
    *reinterpret_cast<bf16x4*>(Ahat + (size_t)row * NN + j) = o;
}

// ---------------- weight transpose: Wt[n][k] = (bf16)W[k][n], W is f32 ----------------
__global__ void transpose_kernel(const float* __restrict__ W, bf16* __restrict__ Wt,
                                 int K, int Nn) {
    int idx = (blockIdx.x * blockDim.x + threadIdx.x) * 8;  // index into Wt (Nn*K elems)
    if (idx >= K * Nn) return;
    int n = idx / K, k0 = idx % K;
    bf16x8 o;
#pragma unroll
    for (int i = 0; i < 8; ++i) o[i] = (bf16)W[(size_t)(k0 + i) * Nn + n];
    *reinterpret_cast<bf16x8*>(Wt + idx) = o;
}

// ---------------- GEMM: Ct[n][m] = sum_k A[m][k] * Wt[n][k] ----------------
// A is f32 (layer 1, AF32=true) or bf16 (hidden layers). Yt stored transposed [128][8192].
// block: 256 thr = 4 waves in 2x2; tile 32 rows x 128 cols; grid 256
template <int K, bool AF32>
__global__ __launch_bounds__(256) void gemm_t_kernel(const void* __restrict__ Av,
                                                     const bf16* __restrict__ Wt,
                                                     bf16* __restrict__ Ct) {
    int wave = threadIdx.x >> 6, lane = threadIdx.x & 63;
    int wr = wave >> 1, wc = wave & 1;
    int lrow = lane & 15, lk = (lane >> 4) * 8;
    int m0 = blockIdx.x * 32 + wr * 16;
    const bf16* Bp = Wt + (size_t)(wc * 64 + lrow) * K + lk;
    f32x4 acc[4] = {};
    if constexpr (AF32) {
        const float* Ap = (const float*)Av + (size_t)(m0 + lrow) * K + lk;
        for (int k = 0; k < K; k += 32) {
            float4 a0 = *reinterpret_cast<const float4*>(Ap + k);
            float4 a1 = *reinterpret_cast<const float4*>(Ap + k + 4);
            bf16x8 a;
            a[0] = (bf16)a0.x; a[1] = (bf16)a0.y; a[2] = (bf16)a0.z; a[3] = (bf16)a0.w;
            a[4] = (bf16)a1.x; a[5] = (bf16)a1.y; a[6] = (bf16)a1.z; a[7] = (bf16)a1.w;
#pragma unroll
            for (int f = 0; f < 4; ++f) {
                bf16x8 bb = *reinterpret_cast<const bf16x8*>(Bp + (size_t)f * 16 * K + k);
                acc[f] = mfma16(a, bb, acc[f]);
            }
        }
    } else {
        const bf16* Ap = (const bf16*)Av + (size_t)(m0 + lrow) * K + lk;
        for (int k = 0; k < K; k += 32) {
            bf16x8 a = *reinterpret_cast<const bf16x8*>(Ap + k);
#pragma unroll
            for (int f = 0; f < 4; ++f) {
                bf16x8 bb = *reinterpret_cast<const bf16x8*>(Bp + (size_t)f * 16 * K + k);
                acc[f] = mfma16(a, bb, acc[f]);
            }
        }
    }
    int rbase = m0 + (lane >> 4) * 4;  // C row = (lane>>4)*4 + reg
#pragma unroll
    for (int f = 0; f < 4; ++f) {
        int col = wc * 64 + f * 16 + lrow;  // C col = lane&15
        bf16x4 o;
#pragma unroll
        for (int r = 0; r < 4; ++r) o[r] = (bf16)acc[f][r];
        *reinterpret_cast<bf16x4*>(Ct + (size_t)col * MROWS + rbase) = o;
    }
}

// ---------------- aggregation: H = relu(Ahat_b @ Y_b + bias), fused layer-average ----------------
// Yt layout: [GH=128][MROWS]. mode: 0 = out  = 0.25*v (and H), 1 = out += 0.25*v (and H),
//                              2 = out += 0.25*v (no H write)
__global__ __launch_bounds__(256) void agg_kernel(const bf16* __restrict__ Ahat,
                                                  const bf16* __restrict__ Yt,
                                                  const float* __restrict__ bias,
                                                  bf16* __restrict__ H,
                                                  float* __restrict__ outp, int mode) {
    int wave = threadIdx.x >> 6, lane = threadIdx.x & 63;
    int wr = wave >> 1, wc = wave & 1;
    int lrow = lane & 15, lk = (lane >> 4) * 8;
    int g0 = blockIdx.x * 32 + wr * 16;  // global row 0..8191
    int b  = g0 >> 10;
    const bf16* Ap = Ahat + (size_t)(g0 + lrow) * NN + lk;
    const bf16* Bp = Yt + (size_t)(wc * 64 + lrow) * MROWS + b * NN + lk;
    f32x4 acc[4] = {};
    for (int k = 0; k < NN; k += 32) {
        bf16x8 a = *reinterpret_cast<const bf16x8*>(Ap + k);
#pragma unroll
        for (int f = 0; f < 4; ++f) {
            bf16x8 bb = *reinterpret_cast<const bf16x8*>(Bp + (size_t)f * 16 * MROWS + k);
            acc[f] = mfma16(a, bb, acc[f]);
        }
    }
    int rbase = g0 + (lane >> 4) * 4;
#pragma unroll
    for (int f = 0; f < 4; ++f) {
        int col = wc * 64 + f * 16 + lrow;
        float bv = bias[col];
#pragma unroll
        for (int r = 0; r < 4; ++r) {
            float v = acc[f][r] + bv;
            v = fmaxf(v, 0.f);
            size_t idx = (size_t)(rbase + r) * GH + col;
            if (mode != 2) H[idx] = (bf16)v;
            if (mode == 0) outp[idx] = 0.25f * v;
            else           outp[idx] += 0.25f * v;
        }
    }
}

extern "C" void kernel_launch(void* const* d_in, const int* in_sizes, int n_in,
                              void* d_out, int out_size, void* d_ws, size_t ws_size,
                              hipStream_t stream) {
    const float* aa    = (const float*)d_in[0];
    const int*   rpa   = (const int*)d_in[1];
    const float* W_in  = (const float*)d_in[2];
    const float* b_in  = (const float*)d_in[3];
    const float* W_h0  = (const float*)d_in[4];
    const float* b_h0  = (const float*)d_in[5];
    const float* W_h1  = (const float*)d_in[6];
    const float* b_h1  = (const float*)d_in[7];
    const float* W_out = (const float*)d_in[8];
    const float* b_out = (const float*)d_in[9];
    float* out = (float*)d_out;

    char* ws = (char*)d_ws;
    size_t off = 0;
    float* dinv = (float*)(ws + off); off += (size_t)MROWS * 4;                 // 32KB
    bf16*  Ahat = (bf16*)(ws + off);  off += (size_t)MROWS * NN * 2;            // 16MB
    bf16*  Yt   = (bf16*)(ws + off);  off += (size_t)GH * MROWS * 2;            // 2MB
    bf16*  H    = (bf16*)(ws + off);  off += (size_t)MROWS * GH * 2;            // 2MB
    bf16*  Wt_in = (bf16*)(ws + off); off += (size_t)GH * GIN * 2;              // 256KB
    bf16*  Wt_h0 = (bf16*)(ws + off); off += (size_t)GH * GH * 2;
    bf16*  Wt_h1 = (bf16*)(ws + off); off += (size_t)GH * GH * 2;
    bf16*  Wt_o  = (bf16*)(ws + off); off += (size_t)GH * GH * 2;

    deg_kernel<<<2048, 256, 0, stream>>>(rpa, dinv);
    ahat_kernel<<<8192, 256, 0, stream>>>(rpa, dinv, Ahat);
    transpose_kernel<<<64, 256, 0, stream>>>(W_in, Wt_in, GIN, GH);
    transpose_kernel<<<8, 256, 0, stream>>>(W_h0, Wt_h0, GH, GH);
    transpose_kernel<<<8, 256, 0, stream>>>(W_h1, Wt_h1, GH, GH);
    transpose_kernel<<<8, 256, 0, stream>>>(W_out, Wt_o, GH, GH);

    gemm_t_kernel<GIN, true><<<256, 256, 0, stream>>>(aa, Wt_in, Yt);
    agg_kernel<<<256, 256, 0, stream>>>(Ahat, Yt, b_in, H, out, 0);
    gemm_t_kernel<GH, false><<<256, 256, 0, stream>>>(H, Wt_h0, Yt);
    agg_kernel<<<256, 256, 0, stream>>>(Ahat, Yt, b_h0, H, out, 1);
    gemm_t_kernel<GH, false><<<256, 256, 0, stream>>>(H, Wt_h1, Yt);
    agg_kernel<<<256, 256, 0, stream>>>(Ahat, Yt, b_h1, H, out, 1);
    gemm_t_kernel<GH, false><<<256, 256, 0, stream>>>(H, Wt_o, Yt);
    agg_kernel<<<256, 256, 0, stream>>>(Ahat, Yt, b_out, H, out, 2);
}

// Round 3
// 160.854 us; speedup vs baseline: 1.0569x; 1.0569x over previous
//
#include <hip/hip_runtime.h>
#include <hip/hip_bf16.h>

typedef __bf16 bf16;
typedef __bf16 bf16x4 __attribute__((ext_vector_type(4)));
typedef __bf16 bf16x8 __attribute__((ext_vector_type(8)));
typedef float f32x4 __attribute__((ext_vector_type(4)));

#define NN 1024
#define GH 128
#define MROWS 8192  // 8*1024

static __device__ __forceinline__ f32x4 mfma16(bf16x8 a, bf16x8 b, f32x4 c) {
    return __builtin_amdgcn_mfma_f32_16x16x32_bf16(a, b, c, 0, 0, 0);
}

// ---------------- prep: A01 (exact 0/1 bf16, diag=1) + dinv = rsqrt(deg) ----------------
// wave per row; block=256 -> 4 rows/block; grid 2048
__global__ __launch_bounds__(256) void prep_kernel(const int* __restrict__ rpa,
                                                   bf16* __restrict__ A01,
                                                   float* __restrict__ dinv) {
    int row  = blockIdx.x * 4 + (threadIdx.x >> 6);
    int lane = threadIdx.x & 63;
    int i = row & (NN - 1);
    const int4* p = reinterpret_cast<const int4*>(rpa + (size_t)row * NN);
    bf16* arow = A01 + (size_t)row * NN;
    int cnt = 0;
#pragma unroll
    for (int it = 0; it < 4; ++it) {
        int4 v = p[lane + it * 64];
        int j = (lane + it * 64) * 4;
        int a0 = (v.x != 0), a1 = (v.y != 0), a2 = (v.z != 0), a3 = (v.w != 0);
        cnt += (a0 & (j + 0 != i)) + (a1 & (j + 1 != i)) +
               (a2 & (j + 2 != i)) + (a3 & (j + 3 != i));
        bf16x4 o;
        o[0] = (bf16)((a0 | (j + 0 == i)) ? 1.f : 0.f);
        o[1] = (bf16)((a1 | (j + 1 == i)) ? 1.f : 0.f);
        o[2] = (bf16)((a2 | (j + 2 == i)) ? 1.f : 0.f);
        o[3] = (bf16)((a3 | (j + 3 == i)) ? 1.f : 0.f);
        *reinterpret_cast<bf16x4*>(arow + j) = o;
    }
#pragma unroll
    for (int off = 32; off > 0; off >>= 1) cnt += __shfl_down(cnt, off, 64);
    if (lane == 0) dinv[row] = rsqrtf((float)(cnt + 1));  // +1 self-loop
}

// ---------------- fused weight transpose: T[n][k] = (bf16)W[k][n] for all 4 weights ----------------
__global__ __launch_bounds__(256) void wtrans_kernel(const float* __restrict__ W0, const float* __restrict__ W1,
                                                     const float* __restrict__ W2, const float* __restrict__ W3,
                                                     bf16* __restrict__ T0, bf16* __restrict__ T1,
                                                     bf16* __restrict__ T2, bf16* __restrict__ T3) {
    int w = blockIdx.y;
    const float* W = (w == 0) ? W0 : (w == 1) ? W1 : (w == 2) ? W2 : W3;
    bf16*       T  = (w == 0) ? T0 : (w == 1) ? T1 : (w == 2) ? T2 : T3;
    int K = (w == 0) ? NN : GH;
    int t = blockIdx.x * 256 + threadIdx.x;
    int n = t & 127;
    int k0 = (t >> 7) * 8;
    if (k0 >= K) return;
    bf16x8 o;
#pragma unroll
    for (int ii = 0; ii < 8; ++ii) o[ii] = (bf16)W[(size_t)(k0 + ii) * GH + n];
    *reinterpret_cast<bf16x8*>(T + (size_t)n * K + k0) = o;
}

// ---------------- GEMM: Zt[n][m] = dinv[m] * sum_k A[m][k] * Wt[n][k] ----------------
// split-K x2: 512 thr = 8 waves = 4 positions (2x2) x 2 K-halves; tile 32r x 128c; grid 256
template <int K, bool AF32>
__global__ __launch_bounds__(512, 2) void gemm_kernel(const void* __restrict__ Av,
                                                      const bf16* __restrict__ Wt,
                                                      const float* __restrict__ dinv,
                                                      bf16* __restrict__ Zt) {
    __shared__ f32x4 red[1024];  // [pos*64+lane][f]
    int wave = threadIdx.x >> 6, lane = threadIdx.x & 63;
    int kh = wave >> 2, pos = wave & 3;
    int wr = pos >> 1, wc = pos & 1;
    int lrow = lane & 15, lk = (lane >> 4) * 8;
    int m0 = blockIdx.x * 32 + wr * 16;
    constexpr int KH = K / 2;
    int kb = kh * KH;
    const bf16* Bp = Wt + (size_t)(wc * 64 + lrow) * K + kb + lk;
    f32x4 acc[4] = {};
    if constexpr (AF32) {
        const float* Ap = (const float*)Av + (size_t)(m0 + lrow) * K + kb + lk;
#pragma unroll 4
        for (int k = 0; k < KH; k += 32) {
            float4 a0 = *reinterpret_cast<const float4*>(Ap + k);
            float4 a1 = *reinterpret_cast<const float4*>(Ap + k + 4);
            bf16x8 a;
            a[0] = (bf16)a0.x; a[1] = (bf16)a0.y; a[2] = (bf16)a0.z; a[3] = (bf16)a0.w;
            a[4] = (bf16)a1.x; a[5] = (bf16)a1.y; a[6] = (bf16)a1.z; a[7] = (bf16)a1.w;
#pragma unroll
            for (int f = 0; f < 4; ++f) {
                bf16x8 bb = *reinterpret_cast<const bf16x8*>(Bp + (size_t)f * 16 * K + k);
                acc[f] = mfma16(a, bb, acc[f]);
            }
        }
    } else {
        const bf16* Ap = (const bf16*)Av + (size_t)(m0 + lrow) * K + kb + lk;
#pragma unroll 4
        for (int k = 0; k < KH; k += 32) {
            bf16x8 a = *reinterpret_cast<const bf16x8*>(Ap + k);
#pragma unroll
            for (int f = 0; f < 4; ++f) {
                bf16x8 bb = *reinterpret_cast<const bf16x8*>(Bp + (size_t)f * 16 * K + k);
                acc[f] = mfma16(a, bb, acc[f]);
            }
        }
    }
    int sidx = (pos * 64 + lane) * 4;
    if (kh == 1) {
#pragma unroll
        for (int f = 0; f < 4; ++f) red[sidx + f] = acc[f];
    }
    __syncthreads();
    if (kh == 0) {
        int rbase = m0 + (lane >> 4) * 4;
        float d0 = dinv[rbase], d1 = dinv[rbase + 1], d2 = dinv[rbase + 2], d3 = dinv[rbase + 3];
#pragma unroll
        for (int f = 0; f < 4; ++f) {
            f32x4 t = acc[f] + red[sidx + f];
            int col = wc * 64 + f * 16 + lrow;
            bf16x4 o;
            o[0] = (bf16)(t[0] * d0);
            o[1] = (bf16)(t[1] * d1);
            o[2] = (bf16)(t[2] * d2);
            o[3] = (bf16)(t[3] * d3);
            *reinterpret_cast<bf16x4*>(Zt + (size_t)col * MROWS + rbase) = o;
        }
    }
}

// ---------------- agg: v = relu(dinv_i * (A01_b @ Z_b) + bias); H=bf16(v); out (+)= 0.25v ----------------
// same split-K structure; Zt layout [GH][MROWS]; mode: 0 '=', 1 '+=', 2 '+=' no H write
__global__ __launch_bounds__(512, 2) void agg_kernel(const bf16* __restrict__ A01,
                                                     const bf16* __restrict__ Zt,
                                                     const float* __restrict__ dinv,
                                                     const float* __restrict__ bias,
                                                     bf16* __restrict__ H,
                                                     float* __restrict__ outp, int mode) {
    __shared__ f32x4 red[1024];
    int wave = threadIdx.x >> 6, lane = threadIdx.x & 63;
    int kh = wave >> 2, pos = wave & 3;
    int wr = pos >> 1, wc = pos & 1;
    int lrow = lane & 15, lk = (lane >> 4) * 8;
    int g0 = blockIdx.x * 32 + wr * 16;
    int b  = blockIdx.x >> 5;  // 32 rows/block, 1024 rows/batch
    constexpr int KH = NN / 2;
    int kb = kh * KH;
    const bf16* Ap = A01 + (size_t)(g0 + lrow) * NN + kb + lk;
    const bf16* Bp = Zt + (size_t)(wc * 64 + lrow) * MROWS + b * NN + kb + lk;
    f32x4 acc[4] = {};
#pragma unroll 4
    for (int k = 0; k < KH; k += 32) {
        bf16x8 a = *reinterpret_cast<const bf16x8*>(Ap + k);
#pragma unroll
        for (int f = 0; f < 4; ++f) {
            bf16x8 bb = *reinterpret_cast<const bf16x8*>(Bp + (size_t)f * 16 * MROWS + k);
            acc[f] = mfma16(a, bb, acc[f]);
        }
    }
    int sidx = (pos * 64 + lane) * 4;
    if (kh == 1) {
#pragma unroll
        for (int f = 0; f < 4; ++f) red[sidx + f] = acc[f];
    }
    __syncthreads();
    if (kh == 0) {
        int rbase = g0 + (lane >> 4) * 4;
        float d0 = dinv[rbase], d1 = dinv[rbase + 1], d2 = dinv[rbase + 2], d3 = dinv[rbase + 3];
#pragma unroll
        for (int f = 0; f < 4; ++f) {
            f32x4 t = acc[f] + red[sidx + f];
            int col = wc * 64 + f * 16 + lrow;
            float bv = bias[col];
            float v0 = fmaxf(t[0] * d0 + bv, 0.f);
            float v1 = fmaxf(t[1] * d1 + bv, 0.f);
            float v2 = fmaxf(t[2] * d2 + bv, 0.f);
            float v3 = fmaxf(t[3] * d3 + bv, 0.f);
            size_t i0 = (size_t)(rbase + 0) * GH + col;
            size_t i1 = (size_t)(rbase + 1) * GH + col;
            size_t i2 = (size_t)(rbase + 2) * GH + col;
            size_t i3 = (size_t)(rbase + 3) * GH + col;
            if (mode != 2) {
                H[i0] = (bf16)v0; H[i1] = (bf16)v1; H[i2] = (bf16)v2; H[i3] = (bf16)v3;
            }
            if (mode == 0) {
                outp[i0] = 0.25f * v0; outp[i1] = 0.25f * v1;
                outp[i2] = 0.25f * v2; outp[i3] = 0.25f * v3;
            } else {
                outp[i0] += 0.25f * v0; outp[i1] += 0.25f * v1;
                outp[i2] += 0.25f * v2; outp[i3] += 0.25f * v3;
            }
        }
    }
}

extern "C" void kernel_launch(void* const* d_in, const int* in_sizes, int n_in,
                              void* d_out, int out_size, void* d_ws, size_t ws_size,
                              hipStream_t stream) {
    const float* aa    = (const float*)d_in[0];
    const int*   rpa   = (const int*)d_in[1];
    const float* W_in  = (const float*)d_in[2];
    const float* b_in  = (const float*)d_in[3];
    const float* W_h0  = (const float*)d_in[4];
    const float* b_h0  = (const float*)d_in[5];
    const float* W_h1  = (const float*)d_in[6];
    const float* b_h1  = (const float*)d_in[7];
    const float* W_out = (const float*)d_in[8];
    const float* b_out = (const float*)d_in[9];
    float* out = (float*)d_out;

    char* ws = (char*)d_ws;
    size_t off = 0;
    float* dinv = (float*)(ws + off); off += (size_t)MROWS * 4;        // 32KB
    bf16*  A01  = (bf16*)(ws + off);  off += (size_t)MROWS * NN * 2;   // 16MB
    bf16*  Zt   = (bf16*)(ws + off);  off += (size_t)GH * MROWS * 2;   // 2MB
    bf16*  H    = (bf16*)(ws + off);  off += (size_t)MROWS * GH * 2;   // 2MB
    bf16*  Wt0  = (bf16*)(ws + off);  off += (size_t)GH * NN * 2;      // 256KB
    bf16*  Wt1  = (bf16*)(ws + off);  off += (size_t)GH * GH * 2;
    bf16*  Wt2  = (bf16*)(ws + off);  off += (size_t)GH * GH * 2;
    bf16*  Wt3  = (bf16*)(ws + off);  off += (size_t)GH * GH * 2;

    prep_kernel<<<2048, 256, 0, stream>>>(rpa, A01, dinv);
    wtrans_kernel<<<dim3(64, 4), 256, 0, stream>>>(W_in, W_h0, W_h1, W_out, Wt0, Wt1, Wt2, Wt3);

    gemm_kernel<NN, true><<<256, 512, 0, stream>>>(aa, Wt0, dinv, Zt);
    agg_kernel<<<256, 512, 0, stream>>>(A01, Zt, dinv, b_in, H, out, 0);
    gemm_kernel<GH, false><<<256, 512, 0, stream>>>(H, Wt1, dinv, Zt);
    agg_kernel<<<256, 512, 0, stream>>>(A01, Zt, dinv, b_h0, H, out, 1);
    gemm_kernel<GH, false><<<256, 512, 0, stream>>>(H, Wt2, dinv, Zt);
    agg_kernel<<<256, 512, 0, stream>>>(A01, Zt, dinv, b_h1, H, out, 1);
    gemm_kernel<GH, false><<<256, 512, 0, stream>>>(H, Wt3, dinv, Zt);
    agg_kernel<<<256, 512, 0, stream>>>(A01, Zt, dinv, b_out, H, out, 2);
}

// Round 4
// 154.529 us; speedup vs baseline: 1.1001x; 1.0409x over previous
//
#include <hip/hip_runtime.h>
#include <hip/hip_bf16.h>

typedef __bf16 bf16;
typedef __bf16 bf16x4 __attribute__((ext_vector_type(4)));
typedef __bf16 bf16x8 __attribute__((ext_vector_type(8)));
typedef float f32x4 __attribute__((ext_vector_type(4)));

#define NN 1024
#define GH 128
#define MROWS 8192  // 8*1024

static __device__ __forceinline__ f32x4 mfma16(bf16x8 a, bf16x8 b, f32x4 c) {
    return __builtin_amdgcn_mfma_f32_16x16x32_bf16(a, b, c, 0, 0, 0);
}

// ---------------- prep: A01 (exact 0/1 bf16, diag=1) + dinv = rsqrt(deg) ----------------
__global__ __launch_bounds__(256) void prep_kernel(const int* __restrict__ rpa,
                                                   bf16* __restrict__ A01,
                                                   float* __restrict__ dinv) {
    int row  = blockIdx.x * 4 + (threadIdx.x >> 6);
    int lane = threadIdx.x & 63;
    int i = row & (NN - 1);
    const int4* p = reinterpret_cast<const int4*>(rpa + (size_t)row * NN);
    bf16* arow = A01 + (size_t)row * NN;
    int cnt = 0;
#pragma unroll
    for (int it = 0; it < 4; ++it) {
        int4 v = p[lane + it * 64];
        int j = (lane + it * 64) * 4;
        int a0 = (v.x != 0), a1 = (v.y != 0), a2 = (v.z != 0), a3 = (v.w != 0);
        cnt += (a0 & (j + 0 != i)) + (a1 & (j + 1 != i)) +
               (a2 & (j + 2 != i)) + (a3 & (j + 3 != i));
        bf16x4 o;
        o[0] = (bf16)((a0 | (j + 0 == i)) ? 1.f : 0.f);
        o[1] = (bf16)((a1 | (j + 1 == i)) ? 1.f : 0.f);
        o[2] = (bf16)((a2 | (j + 2 == i)) ? 1.f : 0.f);
        o[3] = (bf16)((a3 | (j + 3 == i)) ? 1.f : 0.f);
        *reinterpret_cast<bf16x4*>(arow + j) = o;
    }
#pragma unroll
    for (int off = 32; off > 0; off >>= 1) cnt += __shfl_down(cnt, off, 64);
    if (lane == 0) dinv[row] = rsqrtf((float)(cnt + 1));  // +1 self-loop
}

// ---------------- fused weight transpose: T[n][k] = (bf16)W[k][n] ----------------
__global__ __launch_bounds__(256) void wtrans_kernel(const float* __restrict__ W0, const float* __restrict__ W1,
                                                     const float* __restrict__ W2, const float* __restrict__ W3,
                                                     bf16* __restrict__ T0, bf16* __restrict__ T1,
                                                     bf16* __restrict__ T2, bf16* __restrict__ T3) {
    int w = blockIdx.y;
    const float* W = (w == 0) ? W0 : (w == 1) ? W1 : (w == 2) ? W2 : W3;
    bf16*       T  = (w == 0) ? T0 : (w == 1) ? T1 : (w == 2) ? T2 : T3;
    int K = (w == 0) ? NN : GH;
    int t = blockIdx.x * 256 + threadIdx.x;
    int n = t & 127;
    int k0 = (t >> 7) * 8;
    if (k0 >= K) return;
    bf16x8 o;
#pragma unroll
    for (int ii = 0; ii < 8; ++ii) o[ii] = (bf16)W[(size_t)(k0 + ii) * GH + n];
    *reinterpret_cast<bf16x8*>(T + (size_t)n * K + k0) = o;
}

// ---------------- GEMM: Zt[n][m] = dinv[m] * sum_k A[m][k] * Wt[n][k] ----------------
// tile 16 rows x 128 cols; 512 thr = 8 waves = 4 K-quarters x 2 col-halves; grid 512 (2 blk/CU)
template <int K, bool AF32>
__global__ __launch_bounds__(512, 4) void gemm_kernel(const void* __restrict__ Av,
                                                      const bf16* __restrict__ Wt,
                                                      const float* __restrict__ dinv,
                                                      bf16* __restrict__ Zt) {
    __shared__ f32x4 red[1536];  // 6 partial waves x 64 lanes x 4 frags = 24KB
    int wave = threadIdx.x >> 6, lane = threadIdx.x & 63;
    int kh = wave >> 1, ch = wave & 1;
    int lrow = lane & 15, lk = (lane >> 4) * 8;
    int m0 = blockIdx.x * 16;
    constexpr int KH = K / 4;
    int kb = kh * KH;
    const bf16* Bp = Wt + (size_t)(ch * 64 + lrow) * K + kb + lk;
    f32x4 acc[4] = {};
    if constexpr (AF32) {
        const float* Ap = (const float*)Av + (size_t)(m0 + lrow) * K + kb + lk;
#pragma unroll 2
        for (int k = 0; k < KH; k += 32) {
            float4 a0 = *reinterpret_cast<const float4*>(Ap + k);
            float4 a1 = *reinterpret_cast<const float4*>(Ap + k + 4);
            bf16x8 a;
            a[0] = (bf16)a0.x; a[1] = (bf16)a0.y; a[2] = (bf16)a0.z; a[3] = (bf16)a0.w;
            a[4] = (bf16)a1.x; a[5] = (bf16)a1.y; a[6] = (bf16)a1.z; a[7] = (bf16)a1.w;
#pragma unroll
            for (int f = 0; f < 4; ++f) {
                bf16x8 bb = *reinterpret_cast<const bf16x8*>(Bp + (size_t)f * 16 * K + k);
                acc[f] = mfma16(a, bb, acc[f]);
            }
        }
    } else {
        const bf16* Ap = (const bf16*)Av + (size_t)(m0 + lrow) * K + kb + lk;
#pragma unroll 4
        for (int k = 0; k < KH; k += 32) {
            bf16x8 a = *reinterpret_cast<const bf16x8*>(Ap + k);
#pragma unroll
            for (int f = 0; f < 4; ++f) {
                bf16x8 bb = *reinterpret_cast<const bf16x8*>(Bp + (size_t)f * 16 * K + k);
                acc[f] = mfma16(a, bb, acc[f]);
            }
        }
    }
    if (kh != 0) {
        int si = (((kh - 1) * 2 + ch) * 64 + lane) * 4;
#pragma unroll
        for (int f = 0; f < 4; ++f) red[si + f] = acc[f];
    }
    __syncthreads();
    if (kh == 0) {
#pragma unroll
        for (int p = 0; p < 3; ++p) {
            int si = ((p * 2 + ch) * 64 + lane) * 4;
#pragma unroll
            for (int f = 0; f < 4; ++f) acc[f] += red[si + f];
        }
        int rbase = m0 + (lane >> 4) * 4;
        float d0 = dinv[rbase], d1 = dinv[rbase + 1], d2 = dinv[rbase + 2], d3 = dinv[rbase + 3];
#pragma unroll
        for (int f = 0; f < 4; ++f) {
            int col = ch * 64 + f * 16 + lrow;
            bf16x4 o;
            o[0] = (bf16)(acc[f][0] * d0);
            o[1] = (bf16)(acc[f][1] * d1);
            o[2] = (bf16)(acc[f][2] * d2);
            o[3] = (bf16)(acc[f][3] * d3);
            *reinterpret_cast<bf16x4*>(Zt + (size_t)col * MROWS + rbase) = o;
        }
    }
}

// ---------------- agg: v = relu(dinv_i*(A01_b @ Z_b) + bias); H=bf16(v); out (+)= 0.25v ----------------
// same 16x128 tile structure; Zt layout [GH][MROWS]; mode: 0 '=', 1 '+=', 2 '+=' no H
__global__ __launch_bounds__(512, 4) void agg_kernel(const bf16* __restrict__ A01,
                                                     const bf16* __restrict__ Zt,
                                                     const float* __restrict__ dinv,
                                                     const float* __restrict__ bias,
                                                     bf16* __restrict__ H,
                                                     float* __restrict__ outp, int mode) {
    __shared__ f32x4 red[1536];
    int wave = threadIdx.x >> 6, lane = threadIdx.x & 63;
    int kh = wave >> 1, ch = wave & 1;
    int lrow = lane & 15, lk = (lane >> 4) * 8;
    int m0 = blockIdx.x * 16;
    int b  = m0 >> 10;
    constexpr int KH = NN / 4;
    int kb = kh * KH;
    const bf16* Ap = A01 + (size_t)(m0 + lrow) * NN + kb + lk;
    const bf16* Bp = Zt + (size_t)(ch * 64 + lrow) * MROWS + b * NN + kb + lk;
    f32x4 acc[4] = {};
#pragma unroll 4
    for (int k = 0; k < KH; k += 32) {
        bf16x8 a = *reinterpret_cast<const bf16x8*>(Ap + k);
#pragma unroll
        for (int f = 0; f < 4; ++f) {
            bf16x8 bb = *reinterpret_cast<const bf16x8*>(Bp + (size_t)f * 16 * MROWS + k);
            acc[f] = mfma16(a, bb, acc[f]);
        }
    }
    if (kh != 0) {
        int si = (((kh - 1) * 2 + ch) * 64 + lane) * 4;
#pragma unroll
        for (int f = 0; f < 4; ++f) red[si + f] = acc[f];
    }
    __syncthreads();
    if (kh == 0) {
#pragma unroll
        for (int p = 0; p < 3; ++p) {
            int si = ((p * 2 + ch) * 64 + lane) * 4;
#pragma unroll
            for (int f = 0; f < 4; ++f) acc[f] += red[si + f];
        }
        int rbase = m0 + (lane >> 4) * 4;
        float d0 = dinv[rbase], d1 = dinv[rbase + 1], d2 = dinv[rbase + 2], d3 = dinv[rbase + 3];
#pragma unroll
        for (int f = 0; f < 4; ++f) {
            int col = ch * 64 + f * 16 + lrow;
            float bv = bias[col];
            float v0 = fmaxf(acc[f][0] * d0 + bv, 0.f);
            float v1 = fmaxf(acc[f][1] * d1 + bv, 0.f);
            float v2 = fmaxf(acc[f][2] * d2 + bv, 0.f);
            float v3 = fmaxf(acc[f][3] * d3 + bv, 0.f);
            size_t i0 = (size_t)(rbase + 0) * GH + col;
            size_t i1 = (size_t)(rbase + 1) * GH + col;
            size_t i2 = (size_t)(rbase + 2) * GH + col;
            size_t i3 = (size_t)(rbase + 3) * GH + col;
            if (mode != 2) {
                H[i0] = (bf16)v0; H[i1] = (bf16)v1; H[i2] = (bf16)v2; H[i3] = (bf16)v3;
            }
            if (mode == 0) {
                outp[i0] = 0.25f * v0; outp[i1] = 0.25f * v1;
                outp[i2] = 0.25f * v2; outp[i3] = 0.25f * v3;
            } else {
                outp[i0] += 0.25f * v0; outp[i1] += 0.25f * v1;
                outp[i2] += 0.25f * v2; outp[i3] += 0.25f * v3;
            }
        }
    }
}

extern "C" void kernel_launch(void* const* d_in, const int* in_sizes, int n_in,
                              void* d_out, int out_size, void* d_ws, size_t ws_size,
                              hipStream_t stream) {
    const float* aa    = (const float*)d_in[0];
    const int*   rpa   = (const int*)d_in[1];
    const float* W_in  = (const float*)d_in[2];
    const float* b_in  = (const float*)d_in[3];
    const float* W_h0  = (const float*)d_in[4];
    const float* b_h0  = (const float*)d_in[5];
    const float* W_h1  = (const float*)d_in[6];
    const float* b_h1  = (const float*)d_in[7];
    const float* W_out = (const float*)d_in[8];
    const float* b_out = (const float*)d_in[9];
    float* out = (float*)d_out;

    char* ws = (char*)d_ws;
    size_t off = 0;
    float* dinv = (float*)(ws + off); off += (size_t)MROWS * 4;        // 32KB
    bf16*  A01  = (bf16*)(ws + off);  off += (size_t)MROWS * NN * 2;   // 16MB
    bf16*  Zt   = (bf16*)(ws + off);  off += (size_t)GH * MROWS * 2;   // 2MB
    bf16*  H    = (bf16*)(ws + off);  off += (size_t)MROWS * GH * 2;   // 2MB
    bf16*  Wt0  = (bf16*)(ws + off);  off += (size_t)GH * NN * 2;      // 256KB
    bf16*  Wt1  = (bf16*)(ws + off);  off += (size_t)GH * GH * 2;
    bf16*  Wt2  = (bf16*)(ws + off);  off += (size_t)GH * GH * 2;
    bf16*  Wt3  = (bf16*)(ws + off);  off += (size_t)GH * GH * 2;

    prep_kernel<<<2048, 256, 0, stream>>>(rpa, A01, dinv);
    wtrans_kernel<<<dim3(64, 4), 256, 0, stream>>>(W_in, W_h0, W_h1, W_out, Wt0, Wt1, Wt2, Wt3);

    gemm_kernel<NN, true><<<512, 512, 0, stream>>>(aa, Wt0, dinv, Zt);
    agg_kernel<<<512, 512, 0, stream>>>(A01, Zt, dinv, b_in, H, out, 0);
    gemm_kernel<GH, false><<<512, 512, 0, stream>>>(H, Wt1, dinv, Zt);
    agg_kernel<<<512, 512, 0, stream>>>(A01, Zt, dinv, b_h0, H, out, 1);
    gemm_kernel<GH, false><<<512, 512, 0, stream>>>(H, Wt2, dinv, Zt);
    agg_kernel<<<512, 512, 0, stream>>>(A01, Zt, dinv, b_h1, H, out, 1);
    gemm_kernel<GH, false><<<512, 512, 0, stream>>>(H, Wt3, dinv, Zt);
    agg_kernel<<<512, 512, 0, stream>>>(A01, Zt, dinv, b_out, H, out, 2);
}

// Round 5
// 125.989 us; speedup vs baseline: 1.3493x; 1.2265x over previous
//
#include <hip/hip_runtime.h>
#include <hip/hip_bf16.h>

typedef __bf16 bf16;
typedef __bf16 bf16x4 __attribute__((ext_vector_type(4)));
typedef __bf16 bf16x8 __attribute__((ext_vector_type(8)));
typedef float f32x4 __attribute__((ext_vector_type(4)));

#define NN 1024
#define GH 128
#define MROWS 8192  // 8*1024

static __device__ __forceinline__ f32x4 mfma16(bf16x8 a, bf16x8 b, f32x4 c) {
    return __builtin_amdgcn_mfma_f32_16x16x32_bf16(a, b, c, 0, 0, 0);
}

// ---------------- prep (A01 + dinv) fused with weight transposes ----------------
// blocks 0..2047: prep 4 rows each. blocks 2048..2135: Wt[n][k] = (bf16)W[k][n].
__global__ __launch_bounds__(256) void prep_wtrans_kernel(
        const int* __restrict__ rpa,
        const float* __restrict__ W0, const float* __restrict__ W1,
        const float* __restrict__ W2, const float* __restrict__ W3,
        bf16* __restrict__ A01, float* __restrict__ dinv,
        bf16* __restrict__ T0, bf16* __restrict__ T1,
        bf16* __restrict__ T2, bf16* __restrict__ T3) {
    int bid = blockIdx.x;
    if (bid < 2048) {
        int row  = bid * 4 + (threadIdx.x >> 6);
        int lane = threadIdx.x & 63;
        int i = row & (NN - 1);
        const int4* p = reinterpret_cast<const int4*>(rpa + (size_t)row * NN);
        bf16* arow = A01 + (size_t)row * NN;
        int cnt = 0;
#pragma unroll
        for (int it = 0; it < 4; ++it) {
            int4 v = p[lane + it * 64];
            int j = (lane + it * 64) * 4;
            int a0 = (v.x != 0), a1 = (v.y != 0), a2 = (v.z != 0), a3 = (v.w != 0);
            cnt += (a0 & (j + 0 != i)) + (a1 & (j + 1 != i)) +
                   (a2 & (j + 2 != i)) + (a3 & (j + 3 != i));
            bf16x4 o;
            o[0] = (bf16)((a0 | (j + 0 == i)) ? 1.f : 0.f);
            o[1] = (bf16)((a1 | (j + 1 == i)) ? 1.f : 0.f);
            o[2] = (bf16)((a2 | (j + 2 == i)) ? 1.f : 0.f);
            o[3] = (bf16)((a3 | (j + 3 == i)) ? 1.f : 0.f);
            *reinterpret_cast<bf16x4*>(arow + j) = o;
        }
#pragma unroll
        for (int off = 32; off > 0; off >>= 1) cnt += __shfl_down(cnt, off, 64);
        if (lane == 0) dinv[row] = rsqrtf((float)(cnt + 1));  // +1 self-loop
    } else {
        int t = (bid - 2048) * 256 + threadIdx.x;  // 0..22527
        const float* W; bf16* T; int K; int local;
        if (t < 16384)      { W = W0; T = T0; K = NN; local = t; }
        else if (t < 18432) { W = W1; T = T1; K = GH; local = t - 16384; }
        else if (t < 20480) { W = W2; T = T2; K = GH; local = t - 18432; }
        else                { W = W3; T = T3; K = GH; local = t - 20480; }
        int n = local & 127, k0 = (local >> 7) * 8;
        bf16x8 o;
#pragma unroll
        for (int ii = 0; ii < 8; ++ii) o[ii] = (bf16)W[(size_t)(k0 + ii) * GH + n];
        *reinterpret_cast<bf16x8*>(T + (size_t)n * K + k0) = o;
    }
}

// ---------------- GEMM: Xt[n][m] = bf16(dinv[m] * sum_k aa[m][k] * Wt[n][k]) ----------------
// tile 16 rows x 128 cols; 512 thr = 8 waves = 4 K-quarters x 2 col-halves; grid 512
template <int K, bool AF32>
__global__ __launch_bounds__(512, 4) void gemm_kernel(const void* __restrict__ Av,
                                                      const bf16* __restrict__ Wt,
                                                      const float* __restrict__ dinv,
                                                      bf16* __restrict__ Zt) {
    __shared__ f32x4 red[1536];
    int wave = threadIdx.x >> 6, lane = threadIdx.x & 63;
    int kh = wave >> 1, ch = wave & 1;
    int lrow = lane & 15, lk = (lane >> 4) * 8;
    int m0 = blockIdx.x * 16;
    constexpr int KH = K / 4;
    int kb = kh * KH;
    const bf16* Bp = Wt + (size_t)(ch * 64 + lrow) * K + kb + lk;
    f32x4 acc[4] = {};
    if constexpr (AF32) {
        const float* Ap = (const float*)Av + (size_t)(m0 + lrow) * K + kb + lk;
#pragma unroll 2
        for (int k = 0; k < KH; k += 32) {
            float4 a0 = *reinterpret_cast<const float4*>(Ap + k);
            float4 a1 = *reinterpret_cast<const float4*>(Ap + k + 4);
            bf16x8 a;
            a[0] = (bf16)a0.x; a[1] = (bf16)a0.y; a[2] = (bf16)a0.z; a[3] = (bf16)a0.w;
            a[4] = (bf16)a1.x; a[5] = (bf16)a1.y; a[6] = (bf16)a1.z; a[7] = (bf16)a1.w;
#pragma unroll
            for (int f = 0; f < 4; ++f) {
                bf16x8 bb = *reinterpret_cast<const bf16x8*>(Bp + (size_t)f * 16 * K + k);
                acc[f] = mfma16(a, bb, acc[f]);
            }
        }
    } else {
        const bf16* Ap = (const bf16*)Av + (size_t)(m0 + lrow) * K + kb + lk;
#pragma unroll 4
        for (int k = 0; k < KH; k += 32) {
            bf16x8 a = *reinterpret_cast<const bf16x8*>(Ap + k);
#pragma unroll
            for (int f = 0; f < 4; ++f) {
                bf16x8 bb = *reinterpret_cast<const bf16x8*>(Bp + (size_t)f * 16 * K + k);
                acc[f] = mfma16(a, bb, acc[f]);
            }
        }
    }
    if (kh != 0) {
        int si = (((kh - 1) * 2 + ch) * 64 + lane) * 4;
#pragma unroll
        for (int f = 0; f < 4; ++f) red[si + f] = acc[f];
    }
    __syncthreads();
    if (kh == 0) {
#pragma unroll
        for (int p = 0; p < 3; ++p) {
            int si = ((p * 2 + ch) * 64 + lane) * 4;
#pragma unroll
            for (int f = 0; f < 4; ++f) acc[f] += red[si + f];
        }
        int rbase = m0 + (lane >> 4) * 4;
        float4 d4 = *reinterpret_cast<const float4*>(&dinv[rbase]);
#pragma unroll
        for (int f = 0; f < 4; ++f) {
            int col = ch * 64 + f * 16 + lrow;
            bf16x4 o;
            o[0] = (bf16)(acc[f][0] * d4.x);
            o[1] = (bf16)(acc[f][1] * d4.y);
            o[2] = (bf16)(acc[f][2] * d4.z);
            o[3] = (bf16)(acc[f][3] * d4.w);
            *reinterpret_cast<bf16x4*>(Zt + (size_t)col * MROWS + rbase) = o;
        }
    }
}

// ---------------- fused layer: T = A01_b @ Xt_b ; [U = T@W] ; v = relu(D*U + b) ----------------
// Xt layout [GH][MROWS] (= D*h transposed). HASW: epilogue U = T@W via hi/lo bf16 split MFMA.
// MODE: 0 out=0.25v (write Hst), 1 out+=0.25v (write Hst), 2 out+=0.25v (no Hst).
template <int MODE, bool HASW>
__global__ __launch_bounds__(512, 4) void fused_kernel(const bf16* __restrict__ A01,
                                                       const bf16* __restrict__ Xt,
                                                       const bf16* __restrict__ Wt,
                                                       const float* __restrict__ dinv,
                                                       const float* __restrict__ bias,
                                                       bf16* __restrict__ Hst,
                                                       float* __restrict__ outp) {
    __shared__ f32x4 red[1536];   // 24KB split-K reduce
    __shared__ bf16 Wlds[16384];  // 32KB  Wt[col][k], XOR-swizzled
    __shared__ bf16 Ths[2048];    // 4KB   T hi, XOR-swizzled
    __shared__ bf16 Tls[2048];    // 4KB   T lo
    int wave = threadIdx.x >> 6, lane = threadIdx.x & 63;
    int kh = wave >> 1, ch = wave & 1;
    int lrow = lane & 15, lk = (lane >> 4) * 8;
    int m0 = blockIdx.x * 16;
    int b  = blockIdx.x >> 6;
    if constexpr (HASW) {
        const bf16x8* src = reinterpret_cast<const bf16x8*>(Wt);
        bf16x8* dst = reinterpret_cast<bf16x8*>(Wlds);
#pragma unroll
        for (int i = 0; i < 4; ++i) {
            int idx = threadIdx.x * 4 + i;            // x8 units; row = idx>>4
            dst[idx ^ ((idx >> 4) & 7)] = src[idx];
        }
    }
    constexpr int KH = NN / 4;
    int kb = kh * KH;
    const bf16* Ap = A01 + (size_t)(m0 + lrow) * NN + kb + lk;
    const bf16* Bp = Xt + (size_t)(ch * 64 + lrow) * MROWS + b * NN + kb + lk;
    f32x4 acc[4] = {};
#pragma unroll 4
    for (int k = 0; k < KH; k += 32) {
        bf16x8 a = *reinterpret_cast<const bf16x8*>(Ap + k);
#pragma unroll
        for (int f = 0; f < 4; ++f) {
            bf16x8 bb = *reinterpret_cast<const bf16x8*>(Bp + (size_t)f * 16 * MROWS + k);
            acc[f] = mfma16(a, bb, acc[f]);
        }
    }
    if (kh != 0) {
        int si = (((kh - 1) * 2 + ch) * 64 + lane) * 4;
#pragma unroll
        for (int f = 0; f < 4; ++f) red[si + f] = acc[f];
    }
    __syncthreads();
    if (kh == 0) {
#pragma unroll
        for (int p = 0; p < 3; ++p) {
            int si = ((p * 2 + ch) * 64 + lane) * 4;
#pragma unroll
            for (int f = 0; f < 4; ++f) acc[f] += red[si + f];
        }
        if constexpr (!HASW) {
            int rbase = m0 + (lane >> 4) * 4;
            float4 d4 = *reinterpret_cast<const float4*>(&dinv[rbase]);
#pragma unroll
            for (int f = 0; f < 4; ++f) {
                int col = ch * 64 + f * 16 + lrow;
                float bv = bias[col];
                float v0 = fmaxf(acc[f][0] * d4.x + bv, 0.f);
                float v1 = fmaxf(acc[f][1] * d4.y + bv, 0.f);
                float v2 = fmaxf(acc[f][2] * d4.z + bv, 0.f);
                float v3 = fmaxf(acc[f][3] * d4.w + bv, 0.f);
                float* op = outp + (size_t)rbase * GH + col;
                if (MODE == 0) {
                    op[0] = 0.25f * v0; op[GH] = 0.25f * v1;
                    op[2 * GH] = 0.25f * v2; op[3 * GH] = 0.25f * v3;
                } else {
                    op[0] += 0.25f * v0; op[GH] += 0.25f * v1;
                    op[2 * GH] += 0.25f * v2; op[3 * GH] += 0.25f * v3;
                }
                if (MODE != 2) {
                    bf16x4 h4;
                    h4[0] = (bf16)(v0 * d4.x); h4[1] = (bf16)(v1 * d4.y);
                    h4[2] = (bf16)(v2 * d4.z); h4[3] = (bf16)(v3 * d4.w);
                    *reinterpret_cast<bf16x4*>(Hst + (size_t)col * MROWS + rbase) = h4;
                }
            }
        } else {
            // store T as hi+lo bf16 (T = hi + lo; preserves f32 accuracy through MFMA epilogue)
#pragma unroll
            for (int f = 0; f < 4; ++f) {
                int tcol = ch * 64 + f * 16 + lrow;
#pragma unroll
                for (int r = 0; r < 4; ++r) {
                    int trow = (lane >> 4) * 4 + r;
                    float tv = acc[f][r];
                    bf16 hi = (bf16)tv;
                    int ei = trow * 128 + (tcol ^ ((trow & 7) << 3));
                    Ths[ei] = hi;
                    Tls[ei] = (bf16)(tv - (float)hi);
                }
            }
        }
    }
    if constexpr (HASW) {
        __syncthreads();
        // epilogue: wave handles U cols wave*16..+15; K=128
        f32x4 u = {};
        int wcol = wave * 16 + lrow;
#pragma unroll
        for (int ks = 0; ks < 4; ++ks) {
            int e0 = ks * 32 + lk;
            int te = lrow * 128 + (e0 ^ ((lrow & 7) << 3));
            bf16x8 thi = *reinterpret_cast<const bf16x8*>(&Ths[te]);
            bf16x8 tlo = *reinterpret_cast<const bf16x8*>(&Tls[te]);
            bf16x8 wv = reinterpret_cast<const bf16x8*>(Wlds)[wcol * 16 + ((e0 >> 3) ^ (wcol & 7))];
            u = mfma16(thi, wv, u);
            u = mfma16(tlo, wv, u);
        }
        int r0 = (lane >> 4) * 4;
        float4 d4 = *reinterpret_cast<const float4*>(&dinv[m0 + r0]);
        int ocol = wave * 16 + lrow;
        float bv = bias[ocol];
        float v0 = fmaxf(u[0] * d4.x + bv, 0.f);
        float v1 = fmaxf(u[1] * d4.y + bv, 0.f);
        float v2 = fmaxf(u[2] * d4.z + bv, 0.f);
        float v3 = fmaxf(u[3] * d4.w + bv, 0.f);
        float* op = outp + (size_t)(m0 + r0) * GH + ocol;
        if (MODE == 0) {
            op[0] = 0.25f * v0; op[GH] = 0.25f * v1;
            op[2 * GH] = 0.25f * v2; op[3 * GH] = 0.25f * v3;
        } else {
            op[0] += 0.25f * v0; op[GH] += 0.25f * v1;
            op[2 * GH] += 0.25f * v2; op[3 * GH] += 0.25f * v3;
        }
        if (MODE != 2) {
            bf16x4 h4;
            h4[0] = (bf16)(v0 * d4.x); h4[1] = (bf16)(v1 * d4.y);
            h4[2] = (bf16)(v2 * d4.z); h4[3] = (bf16)(v3 * d4.w);
            *reinterpret_cast<bf16x4*>(Hst + (size_t)ocol * MROWS + m0 + r0) = h4;
        }
    }
}

extern "C" void kernel_launch(void* const* d_in, const int* in_sizes, int n_in,
                              void* d_out, int out_size, void* d_ws, size_t ws_size,
                              hipStream_t stream) {
    const float* aa    = (const float*)d_in[0];
    const int*   rpa   = (const int*)d_in[1];
    const float* W_in  = (const float*)d_in[2];
    const float* b_in  = (const float*)d_in[3];
    const float* W_h0  = (const float*)d_in[4];
    const float* b_h0  = (const float*)d_in[5];
    const float* W_h1  = (const float*)d_in[6];
    const float* b_h1  = (const float*)d_in[7];
    const float* W_out = (const float*)d_in[8];
    const float* b_out = (const float*)d_in[9];
    float* out = (float*)d_out;

    char* ws = (char*)d_ws;
    size_t off = 0;
    float* dinv = (float*)(ws + off); off += (size_t)MROWS * 4;        // 32KB
    bf16*  A01  = (bf16*)(ws + off);  off += (size_t)MROWS * NN * 2;   // 16MB
    bf16*  Xt0  = (bf16*)(ws + off);  off += (size_t)GH * MROWS * 2;   // 2MB
    bf16*  HstA = (bf16*)(ws + off);  off += (size_t)GH * MROWS * 2;   // 2MB
    bf16*  HstB = (bf16*)(ws + off);  off += (size_t)GH * MROWS * 2;   // 2MB
    bf16*  Wt0  = (bf16*)(ws + off);  off += (size_t)GH * NN * 2;      // 256KB
    bf16*  Wt1  = (bf16*)(ws + off);  off += (size_t)GH * GH * 2;
    bf16*  Wt2  = (bf16*)(ws + off);  off += (size_t)GH * GH * 2;
    bf16*  Wt3  = (bf16*)(ws + off);  off += (size_t)GH * GH * 2;

    prep_wtrans_kernel<<<2136, 256, 0, stream>>>(rpa, W_in, W_h0, W_h1, W_out,
                                                 A01, dinv, Wt0, Wt1, Wt2, Wt3);
    gemm_kernel<NN, true><<<512, 512, 0, stream>>>(aa, Wt0, dinv, Xt0);
    fused_kernel<0, false><<<512, 512, 0, stream>>>(A01, Xt0, Wt1, dinv, b_in, HstA, out);
    fused_kernel<1, true><<<512, 512, 0, stream>>>(A01, HstA, Wt1, dinv, b_h0, HstB, out);
    fused_kernel<1, true><<<512, 512, 0, stream>>>(A01, HstB, Wt2, dinv, b_h1, HstA, out);
    fused_kernel<2, true><<<512, 512, 0, stream>>>(A01, HstA, Wt3, dinv, b_out, HstB, out);
}